// Round 9
// baseline (586.891 us; speedup 1.0000x reference)
//
#include <hip/hip_runtime.h>
#include <hip/hip_bf16.h>
#include <stdint.h>

#define B_DIM 4096
#define T_DIM 8
#define IN_DIM 1024
#define OUT_DIM 1024
#define R_DIM 32

#define BM 256
#define BN 256
#define BK 64
#define NKT (IN_DIM / BK)   // 16

typedef __bf16 bf16x8 __attribute__((ext_vector_type(8)));
typedef float  f32x4  __attribute__((ext_vector_type(4)));

#define VMCNT(n) asm volatile("s_waitcnt vmcnt(" #n ")" ::: "memory")
#define CFENCE() asm volatile("" ::: "memory")
#define BARRIER() do { CFENCE(); __builtin_amdgcn_s_barrier(); CFENCE(); } while (0)

// ---- helpers --------------------------------------------------------------

// round-to-nearest fp32->bf16, two packed into one u32 (lo in low half)
__device__ __forceinline__ uint32_t pack2_bf16(float a, float b) {
  uint32_t ua = __float_as_uint(a), ub = __float_as_uint(b);
  ua = (ua + 0x7FFFu + ((ua >> 16) & 1u)) >> 16;
  ub = (ub + 0x7FFFu + ((ub >> 16) & 1u)) & 0xFFFF0000u;
  return ua | ub;
}

// async global->LDS, 16B per lane; LDS dest is wave-uniform base + lane*16
__device__ __forceinline__ void gload_lds16(const void* g, void* l) {
  __builtin_amdgcn_global_load_lds(
      (const __attribute__((address_space(1))) void*)(uintptr_t)g,
      (__attribute__((address_space(3))) void*)(uint32_t)(uintptr_t)l,
      16, 0, 0);
}

// stage one 16KB half-tile (128 of 256 rows, 16-row-interleaved) of a K-tile
// into a 32KB LDS operand region. Linear dest + pre-swizzled source (rule 21).
__device__ __forceinline__ void stage_half(const uint16_t* gtile, int ktn,
                                           int half, uint8_t* ldsop,
                                           int wave, int lane) {
#pragma unroll
  for (int j = 0; j < 2; ++j) {
    int s = j * 64 + wave * 8 + (lane >> 3);      // slot 0..127 within half
    int c = lane & 7;                             // LDS 16B chunk within row
    int row = (s >> 4) * 32 + half * 16 + (s & 15);
    gload_lds16((const uint8_t*)(gtile + (size_t)row * IN_DIM + ktn * BK) +
                    ((c ^ (s & 7)) << 4),
                ldsop + half * 16384 + j * 8192 + wave * 1024);
  }
}

// fragment reads: slot = (row>>5)*16 + (row&15); chunk = (ks*4+kg) ^ (row&7)
__device__ __forceinline__ bf16x8 lds_frag(const uint8_t* op, int grp,
                                           int par, int ks,
                                           int l15, int kg, int l7) {
  return *(const bf16x8*)(op + par * 16384 + (grp >> 1) * 2048 + l15 * 128 +
                          ((((ks << 2) + kg) ^ l7) << 4));
}

// cvt helper: 32 fp32 -> 32 bf16 (8 float4 in, 4 uint4 out)
__device__ __forceinline__ void cvt32(const float* src, uint16_t* dst) {
  float4 v[8];
#pragma unroll
  for (int i = 0; i < 8; ++i) v[i] = *(const float4*)(src + i * 4);
#pragma unroll
  for (int i = 0; i < 4; ++i) {
    uint4 o;
    o.x = pack2_bf16(v[2 * i].x, v[2 * i].y);
    o.y = pack2_bf16(v[2 * i].z, v[2 * i].w);
    o.z = pack2_bf16(v[2 * i + 1].x, v[2 * i + 1].y);
    o.w = pack2_bf16(v[2 * i + 1].z, v[2 * i + 1].w);
    *(uint4*)(dst + i * 8) = o;
  }
}

// ---- L1: stage1 (blocks 0..1023) + x-cvt tasks 0-3 (blocks 1024..3071) ----
__global__ __launch_bounds__(256) void pre1(const float* __restrict__ first,
                                            const float* __restrict__ middle,
                                            float* __restrict__ a1,
                                            const float* __restrict__ x,
                                            uint16_t* __restrict__ xb) {
  int bid = blockIdx.x, tid = threadIdx.x;
  if (bid < 1024) {
    // A1[t][i][k] = sum_j first[t][j] * middle[j][i][k]
    int idx = bid * 256 + tid;                 // t*32768 + i*32 + k
    int t  = idx >> 15;
    int ik = idx & 32767;
    float acc = 0.f;
#pragma unroll
    for (int j = 0; j < R_DIM; ++j)
      acc = fmaf(first[t * R_DIM + j], middle[j * (IN_DIM * R_DIM) + ik], acc);
    a1[idx] = acc;
  } else {
    // cvt x[b][t][:] (t=0..3) -> xb[t][b][:] ; 8 rows per block
    int cb = bid - 1024;                       // 0..2047
    int row_in = tid >> 5;                     // 0..7
    int c0 = (tid & 31) * 32;                  // 32 floats per thread
    int R = cb * 8 + row_in;                   // 0..16383
    int b = R >> 2, t = R & 3;
    cvt32(x + ((size_t)b * T_DIM + t) * IN_DIM + c0,
          xb + ((size_t)t * B_DIM + b) * IN_DIM + c0);
  }
}

// ---- L2: stage2 (blocks 0..2047) + x-cvt tasks 4-7 (blocks 2048..4095) ----
__global__ __launch_bounds__(256) void pre2(const float* __restrict__ a1,
                                            const float* __restrict__ task,
                                            __hip_bfloat16* __restrict__ wT,
                                            const float* __restrict__ x,
                                            uint16_t* __restrict__ xb) {
  int bid = blockIdx.x;
  int tid = threadIdx.x;
  if (bid < 2048) {
    // w_T[t][o][i] = sum_k A1[t][i][k]*task[k][o]
    int t  = bid >> 8;
    int ob = (bid >> 4) & 15;
    int ib = bid & 15;
    __shared__ float A1s[64][33];
    __shared__ float Ts[32][64];
#pragma unroll
    for (int r = 0; r < 8; ++r) {
      int idx2 = tid + 256 * r;
      int il = idx2 >> 5, k = idx2 & 31;
      A1s[il][k] = a1[t * (IN_DIM * R_DIM) + (ib * 64 + il) * R_DIM + k];
    }
#pragma unroll
    for (int r = 0; r < 8; ++r) {
      int idx2 = tid + 256 * r;
      int k = idx2 >> 6, ol = idx2 & 63;
      Ts[k][ol] = task[k * OUT_DIM + ob * 64 + ol];
    }
    __syncthreads();
    int il = tid & 63;
    int og = tid >> 6;
    float acc[16];
#pragma unroll
    for (int r = 0; r < 16; ++r) acc[r] = 0.f;
#pragma unroll
    for (int k = 0; k < 32; ++k) {
      float a = A1s[il][k];
#pragma unroll
      for (int r = 0; r < 16; ++r)
        acc[r] = fmaf(a, Ts[k][og * 16 + r], acc[r]);
    }
#pragma unroll
    for (int r = 0; r < 16; ++r) {
      size_t o = (size_t)ob * 64 + og * 16 + r;
      wT[((size_t)t * OUT_DIM + o) * IN_DIM + ib * 64 + il] = __float2bfloat16(acc[r]);
    }
  } else {
    // cvt tasks 4-7 ; 8 rows per block
    int cb = bid - 2048;                       // 0..2047
    int row_in = tid >> 5;
    int c0 = (tid & 31) * 32;
    int R = cb * 8 + row_in;                   // 0..16383
    int b = R >> 2, t = 4 + (R & 3);
    cvt32(x + ((size_t)b * T_DIM + t) * IN_DIM + c0,
          xb + ((size_t)t * B_DIM + b) * IN_DIM + c0);
  }
}

// ---- GEMM: 256x256xBK64 8-phase, SINGLE-buffer half-ping-pong (64KB LDS) --
// LDS: Ah0 @0, Ah1 @16K, Bh0 @32K, Bh1 @48K. The 8-phase schedule frees each
// half before its restage phase: h0(kt) last read in P1 (consumed by P1 MFMA
// before its closing barrier) -> stage h0(kt+1) in P2; h1(kt) last read in
// P2/P3 -> stage h1(kt+1) in P4. 64KB -> 2 blocks/CU: the co-resident block
// fills barrier stalls and the epilogue C-drain (m114 mechanism).
// Waits: P4-end VMCNT(4) (drains h0(kt+1), keeps h1(kt+1) flying);
//        P1-end VMCNT(0) (queue = 4x h1(kt), 2-phase-old L2-warm).
__global__ __launch_bounds__(512, 4) void tt_gemm(const uint16_t* __restrict__ XB,
                                                  const uint16_t* __restrict__ WT,
                                                  float* __restrict__ O) {
  extern __shared__ uint8_t sm[];
  int bid = blockIdx.x;
  const int t  = bid & 7;                 // task == XCD (round-robin dispatch)
  const int l  = bid >> 3;                // 0..63 within task
  const int mt = l >> 2;                  // 0..15
  const int nt = l & 3;                   // n-fastest: x panel L2-shared

  const int tid  = threadIdx.x;
  const int lane = tid & 63;
  const int wave = tid >> 6;              // 0..7
  const int wr = wave >> 2, wc = wave & 3;
  const int wr8 = wr * 8, wc4 = wc * 4;
  const int l15 = lane & 15, l7 = lane & 7, kg = lane >> 4;

  const uint16_t* gA = XB + ((size_t)t * B_DIM + mt * BM) * IN_DIM;
  const uint16_t* gB = WT + ((size_t)t * OUT_DIM + nt * BN) * IN_DIM;

  uint8_t* bA = sm;            // A: h0 @0, h1 @16384
  uint8_t* bB = sm + 32768;    // B: h0 @0, h1 @16384

  f32x4 acc[8][4] = {};
  bf16x8 afr[4][2], bfr0[2][2], bfr1[2][2];

  // ---- prologue: K-tile 0, both halves; drain h0 only (h1 drains at P1-end)
  stage_half(gA, 0, 0, bA, wave, lane);
  stage_half(gB, 0, 0, bB, wave, lane);
  stage_half(gA, 0, 1, bA, wave, lane);
  stage_half(gB, 0, 1, bB, wave, lane);
  VMCNT(4);                    // h0(0) ready; h1(0) still flying
  BARRIER();

  for (int kt = 0; kt < NKT; ++kt) {
    const bool st = (kt + 1) < NKT;

    // ===== P1: (mp0, np0) — reads h0(kt); h0 slots free after this phase
#pragma unroll
    for (int mo = 0; mo < 4; ++mo)
#pragma unroll
      for (int ks = 0; ks < 2; ++ks)
        afr[mo][ks] = lds_frag(bA, wr8 + mo * 2, 0, ks, l15, kg, l7);
#pragma unroll
    for (int no = 0; no < 2; ++no)
#pragma unroll
      for (int ks = 0; ks < 2; ++ks)
        bfr0[no][ks] = lds_frag(bB, wc4 + no * 2, 0, ks, l15, kg, l7);
    VMCNT(0);                  // h1(kt) ready (staged P4(kt-1), 2-phase cover)
    BARRIER();
    __builtin_amdgcn_s_setprio(1);
#pragma unroll
    for (int mo = 0; mo < 4; ++mo)
#pragma unroll
      for (int no = 0; no < 2; ++no)
#pragma unroll
        for (int ks = 0; ks < 2; ++ks)
          acc[mo * 2][no * 2] = __builtin_amdgcn_mfma_f32_16x16x32_bf16(
              afr[mo][ks], bfr0[no][ks], acc[mo * 2][no * 2], 0, 0, 0);
    __builtin_amdgcn_s_setprio(0);
    BARRIER();

    // ===== P2: (mp0, np1) — reads Bh1(kt); stage h0(kt+1) into freed slots
#pragma unroll
    for (int no = 0; no < 2; ++no)
#pragma unroll
      for (int ks = 0; ks < 2; ++ks)
        bfr1[no][ks] = lds_frag(bB, wc4 + no * 2 + 1, 1, ks, l15, kg, l7);
    if (st) {
      stage_half(gA, kt + 1, 0, bA, wave, lane);
      stage_half(gB, kt + 1, 0, bB, wave, lane);
    }
    BARRIER();
    __builtin_amdgcn_s_setprio(1);
#pragma unroll
    for (int mo = 0; mo < 4; ++mo)
#pragma unroll
      for (int no = 0; no < 2; ++no)
#pragma unroll
        for (int ks = 0; ks < 2; ++ks)
          acc[mo * 2][no * 2 + 1] = __builtin_amdgcn_mfma_f32_16x16x32_bf16(
              afr[mo][ks], bfr1[no][ks], acc[mo * 2][no * 2 + 1], 0, 0, 0);
    __builtin_amdgcn_s_setprio(0);
    BARRIER();

    // ===== P3: (mp1, np0) — reads Ah1(kt); bfr0 kept live from P1
#pragma unroll
    for (int mo = 0; mo < 4; ++mo)
#pragma unroll
      for (int ks = 0; ks < 2; ++ks)
        afr[mo][ks] = lds_frag(bA, wr8 + mo * 2 + 1, 1, ks, l15, kg, l7);
    BARRIER();
    __builtin_amdgcn_s_setprio(1);
#pragma unroll
    for (int mo = 0; mo < 4; ++mo)
#pragma unroll
      for (int no = 0; no < 2; ++no)
#pragma unroll
        for (int ks = 0; ks < 2; ++ks)
          acc[mo * 2 + 1][no * 2] = __builtin_amdgcn_mfma_f32_16x16x32_bf16(
              afr[mo][ks], bfr0[no][ks], acc[mo * 2 + 1][no * 2], 0, 0, 0);
    __builtin_amdgcn_s_setprio(0);
    BARRIER();

    // ===== P4: (mp1, np1) — stage h1(kt+1) into freed slots
    if (st) {
      stage_half(gA, kt + 1, 1, bA, wave, lane);
      stage_half(gB, kt + 1, 1, bB, wave, lane);
      VMCNT(4);                // h0(kt+1) ready (staged P2, 2-phase cover);
                               // h1(kt+1) stays in flight
    }
    BARRIER();
    __builtin_amdgcn_s_setprio(1);
#pragma unroll
    for (int mo = 0; mo < 4; ++mo)
#pragma unroll
      for (int no = 0; no < 2; ++no)
#pragma unroll
        for (int ks = 0; ks < 2; ++ks)
          acc[mo * 2 + 1][no * 2 + 1] = __builtin_amdgcn_mfma_f32_16x16x32_bf16(
              afr[mo][ks], bfr1[no][ks], acc[mo * 2 + 1][no * 2 + 1], 0, 0, 0);
    __builtin_amdgcn_s_setprio(0);
    BARRIER();
  }

  // ---- epilogue: C/D layout col=lane&15, row=(lane>>4)*4+j (m89-verified)
  const int crow0 = mt * BM + wr * 128 + (lane >> 4) * 4;
  const int ccol0 = nt * BN + wc * 64 + (lane & 15);
#pragma unroll
  for (int m = 0; m < 8; ++m) {
#pragma unroll
    for (int j = 0; j < 4; ++j) {
      size_t rowoff =
          ((size_t)(crow0 + m * 16 + j) * T_DIM + t) * OUT_DIM + ccol0;
#pragma unroll
      for (int n = 0; n < 4; ++n)
        O[rowoff + n * 16] = acc[m][n][j];
    }
  }
}

// ---- host ------------------------------------------------------------------
extern "C" void kernel_launch(void* const* d_in, const int* in_sizes, int n_in,
                              void* d_out, int out_size, void* d_ws, size_t ws_size,
                              hipStream_t stream) {
  const float* x      = (const float*)d_in[0];
  const float* first  = (const float*)d_in[1];
  const float* middle = (const float*)d_in[2];
  const float* task   = (const float*)d_in[3];
  float* out = (float*)d_out;

  // ws: a1 fp32 1MB @0; wT bf16 16MB @1MB; xb bf16 64MB @17MB
  float* a1 = (float*)d_ws;
  __hip_bfloat16* wT = (__hip_bfloat16*)((uint8_t*)d_ws + (1u << 20));
  uint16_t* xb = (uint16_t*)((uint8_t*)d_ws + (17u << 20));

  hipFuncSetAttribute((const void*)tt_gemm,
                      hipFuncAttributeMaxDynamicSharedMemorySize, 65536);

  // L1: stage1 + cvt(t0-3)   (3072 blocks)
  pre1<<<3072, 256, 0, stream>>>(first, middle, a1, x, xb);
  // L2: stage2 + cvt(t4-7)   (4096 blocks)
  pre2<<<4096, 256, 0, stream>>>(a1, task, wT, x, xb);
  // L3: single 512-block GEMM, 64KB LDS -> 2 blocks/CU
  tt_gemm<<<T_DIM * (B_DIM / BM) * (OUT_DIM / BN), 512, 65536, stream>>>(
      xb, (const uint16_t*)wT, out);
}

// Round 10
// 152.400 us; speedup vs baseline: 3.8510x; 3.8510x over previous
//
#include <hip/hip_runtime.h>
#include <hip/hip_bf16.h>
#include <stdint.h>

#define B_DIM 4096
#define T_DIM 8
#define IN_DIM 1024
#define OUT_DIM 1024
#define R_DIM 32

#define BM 256
#define BN 256
#define BK 64
#define NKT (IN_DIM / BK)   // 16

typedef __bf16 bf16x8 __attribute__((ext_vector_type(8)));
typedef float  f32x4  __attribute__((ext_vector_type(4)));

#define VMCNT(n) asm volatile("s_waitcnt vmcnt(" #n ")" ::: "memory")
#define CFENCE() asm volatile("" ::: "memory")
#define BARRIER() do { CFENCE(); __builtin_amdgcn_s_barrier(); CFENCE(); } while (0)

// ---- helpers --------------------------------------------------------------

// round-to-nearest fp32->bf16, two packed into one u32 (lo in low half)
__device__ __forceinline__ uint32_t pack2_bf16(float a, float b) {
  uint32_t ua = __float_as_uint(a), ub = __float_as_uint(b);
  ua = (ua + 0x7FFFu + ((ua >> 16) & 1u)) >> 16;
  ub = (ub + 0x7FFFu + ((ub >> 16) & 1u)) & 0xFFFF0000u;
  return ua | ub;
}

// async global->LDS, 16B per lane; LDS dest is wave-uniform base + lane*16
__device__ __forceinline__ void gload_lds16(const void* g, void* l) {
  __builtin_amdgcn_global_load_lds(
      (const __attribute__((address_space(1))) void*)(uintptr_t)g,
      (__attribute__((address_space(3))) void*)(uint32_t)(uintptr_t)l,
      16, 0, 0);
}

// stage one 16KB half-tile (128 of 256 rows, 16-row-interleaved) of a K-tile
// into a 32KB LDS operand region. Linear dest + pre-swizzled source (rule 21).
__device__ __forceinline__ void stage_half(const uint16_t* gtile, int ktn,
                                           int half, uint8_t* ldsop,
                                           int wave, int lane) {
#pragma unroll
  for (int j = 0; j < 2; ++j) {
    int s = j * 64 + wave * 8 + (lane >> 3);      // slot 0..127 within half
    int c = lane & 7;                             // LDS 16B chunk within row
    int row = (s >> 4) * 32 + half * 16 + (s & 15);
    gload_lds16((const uint8_t*)(gtile + (size_t)row * IN_DIM + ktn * BK) +
                    ((c ^ (s & 7)) << 4),
                ldsop + half * 16384 + j * 8192 + wave * 1024);
  }
}

// fragment reads: slot = (row>>5)*16 + (row&15); chunk = (ks*4+kg) ^ (row&7)
__device__ __forceinline__ bf16x8 lds_frag(const uint8_t* op, int grp,
                                           int par, int ks,
                                           int l15, int kg, int l7) {
  return *(const bf16x8*)(op + par * 16384 + (grp >> 1) * 2048 + l15 * 128 +
                          ((((ks << 2) + kg) ^ l7) << 4));
}

// cvt helper: 32 fp32 -> 32 bf16 (8 float4 in, 4 uint4 out)
__device__ __forceinline__ void cvt32(const float* src, uint16_t* dst) {
  float4 v[8];
#pragma unroll
  for (int i = 0; i < 8; ++i) v[i] = *(const float4*)(src + i * 4);
#pragma unroll
  for (int i = 0; i < 4; ++i) {
    uint4 o;
    o.x = pack2_bf16(v[2 * i].x, v[2 * i].y);
    o.y = pack2_bf16(v[2 * i].z, v[2 * i].w);
    o.z = pack2_bf16(v[2 * i + 1].x, v[2 * i + 1].y);
    o.w = pack2_bf16(v[2 * i + 1].z, v[2 * i + 1].w);
    *(uint4*)(dst + i * 8) = o;
  }
}

// ---- L1: stage1 (blocks 0..1023) + x-cvt tasks 0-3 (blocks 1024..3071) ----
__global__ __launch_bounds__(256) void pre1(const float* __restrict__ first,
                                            const float* __restrict__ middle,
                                            float* __restrict__ a1,
                                            const float* __restrict__ x,
                                            uint16_t* __restrict__ xb) {
  int bid = blockIdx.x, tid = threadIdx.x;
  if (bid < 1024) {
    // A1[t][i][k] = sum_j first[t][j] * middle[j][i][k]
    int idx = bid * 256 + tid;                 // t*32768 + i*32 + k
    int t  = idx >> 15;
    int ik = idx & 32767;
    float acc = 0.f;
#pragma unroll
    for (int j = 0; j < R_DIM; ++j)
      acc = fmaf(first[t * R_DIM + j], middle[j * (IN_DIM * R_DIM) + ik], acc);
    a1[idx] = acc;
  } else {
    // cvt x[b][t][:] (t=0..3) -> xb[t][b][:] ; 8 rows per block
    int cb = bid - 1024;                       // 0..2047
    int row_in = tid >> 5;                     // 0..7
    int c0 = (tid & 31) * 32;                  // 32 floats per thread
    int R = cb * 8 + row_in;                   // 0..16383
    int b = R >> 2, t = R & 3;
    cvt32(x + ((size_t)b * T_DIM + t) * IN_DIM + c0,
          xb + ((size_t)t * B_DIM + b) * IN_DIM + c0);
  }
}

// ---- L2: stage2 (blocks 0..2047) + x-cvt tasks 4-7 (blocks 2048..4095) ----
__global__ __launch_bounds__(256) void pre2(const float* __restrict__ a1,
                                            const float* __restrict__ task,
                                            __hip_bfloat16* __restrict__ wT,
                                            const float* __restrict__ x,
                                            uint16_t* __restrict__ xb) {
  int bid = blockIdx.x;
  int tid = threadIdx.x;
  if (bid < 2048) {
    // w_T[t][o][i] = sum_k A1[t][i][k]*task[k][o]
    int t  = bid >> 8;
    int ob = (bid >> 4) & 15;
    int ib = bid & 15;
    __shared__ float A1s[64][33];
    __shared__ float Ts[32][64];
#pragma unroll
    for (int r = 0; r < 8; ++r) {
      int idx2 = tid + 256 * r;
      int il = idx2 >> 5, k = idx2 & 31;
      A1s[il][k] = a1[t * (IN_DIM * R_DIM) + (ib * 64 + il) * R_DIM + k];
    }
#pragma unroll
    for (int r = 0; r < 8; ++r) {
      int idx2 = tid + 256 * r;
      int k = idx2 >> 6, ol = idx2 & 63;
      Ts[k][ol] = task[k * OUT_DIM + ob * 64 + ol];
    }
    __syncthreads();
    int il = tid & 63;
    int og = tid >> 6;
    float acc[16];
#pragma unroll
    for (int r = 0; r < 16; ++r) acc[r] = 0.f;
#pragma unroll
    for (int k = 0; k < 32; ++k) {
      float a = A1s[il][k];
#pragma unroll
      for (int r = 0; r < 16; ++r)
        acc[r] = fmaf(a, Ts[k][og * 16 + r], acc[r]);
    }
#pragma unroll
    for (int r = 0; r < 16; ++r) {
      size_t o = (size_t)ob * 64 + og * 16 + r;
      wT[((size_t)t * OUT_DIM + o) * IN_DIM + ib * 64 + il] = __float2bfloat16(acc[r]);
    }
  } else {
    // cvt tasks 4-7 ; 8 rows per block
    int cb = bid - 2048;                       // 0..2047
    int row_in = tid >> 5;
    int c0 = (tid & 31) * 32;
    int R = cb * 8 + row_in;                   // 0..16383
    int b = R >> 2, t = 4 + (R & 3);
    cvt32(x + ((size_t)b * T_DIM + t) * IN_DIM + c0,
          xb + ((size_t)t * B_DIM + b) * IN_DIM + c0);
  }
}

// ---- GEMM: 256x256xBK64 8-phase, SINGLE-buffer half-ping-pong (64KB LDS) --
// LDS: Ah0 @0, Ah1 @16K, Bh0 @32K, Bh1 @48K. The 8-phase schedule frees each
// half before its restage phase: h0(kt) last read in P1 -> stage h0(kt+1) in
// P2; h1(kt) last read in P2/P3 -> stage h1(kt+1) in P4.
// LAUNCH BOUNDS (512,2): R9's (512,4) forced a 64-VGPR budget and spilled the
// 128-reg accumulator (FETCH 900MB / WRITE 1.4GB scratch traffic). (512,2)
// gives 128 VGPR (R4-proven, no spill); VGPR then caps occupancy at 16
// waves/CU = 2 blocks/CU -> cross-block overlap of stalls + C-drain (m114).
// Waits: P4-end VMCNT(4) (drains h0(kt+1), keeps h1(kt+1) flying);
//        P1-end VMCNT(0) (queue = 4x h1(kt), staged one phase earlier).
__global__ __launch_bounds__(512, 2) void tt_gemm(const uint16_t* __restrict__ XB,
                                                  const uint16_t* __restrict__ WT,
                                                  float* __restrict__ O) {
  extern __shared__ uint8_t sm[];
  int bid = blockIdx.x;
  const int t  = bid & 7;                 // task == XCD (round-robin dispatch)
  const int l  = bid >> 3;                // 0..63 within task
  const int mt = l >> 2;                  // 0..15
  const int nt = l & 3;                   // n-fastest: x panel L2-shared

  const int tid  = threadIdx.x;
  const int lane = tid & 63;
  const int wave = tid >> 6;              // 0..7
  const int wr = wave >> 2, wc = wave & 3;
  const int wr8 = wr * 8, wc4 = wc * 4;
  const int l15 = lane & 15, l7 = lane & 7, kg = lane >> 4;

  const uint16_t* gA = XB + ((size_t)t * B_DIM + mt * BM) * IN_DIM;
  const uint16_t* gB = WT + ((size_t)t * OUT_DIM + nt * BN) * IN_DIM;

  uint8_t* bA = sm;            // A: h0 @0, h1 @16384
  uint8_t* bB = sm + 32768;    // B: h0 @0, h1 @16384

  f32x4 acc[8][4] = {};
  bf16x8 afr[4][2], bfr0[2][2], bfr1[2][2];

  // ---- prologue: K-tile 0, both halves; drain h0 only (h1 drains at P1-end)
  stage_half(gA, 0, 0, bA, wave, lane);
  stage_half(gB, 0, 0, bB, wave, lane);
  stage_half(gA, 0, 1, bA, wave, lane);
  stage_half(gB, 0, 1, bB, wave, lane);
  VMCNT(4);                    // h0(0) ready; h1(0) still flying
  BARRIER();

  for (int kt = 0; kt < NKT; ++kt) {
    const bool st = (kt + 1) < NKT;

    // ===== P1: (mp0, np0) — reads h0(kt); h0 slots free after this phase
#pragma unroll
    for (int mo = 0; mo < 4; ++mo)
#pragma unroll
      for (int ks = 0; ks < 2; ++ks)
        afr[mo][ks] = lds_frag(bA, wr8 + mo * 2, 0, ks, l15, kg, l7);
#pragma unroll
    for (int no = 0; no < 2; ++no)
#pragma unroll
      for (int ks = 0; ks < 2; ++ks)
        bfr0[no][ks] = lds_frag(bB, wc4 + no * 2, 0, ks, l15, kg, l7);
    VMCNT(0);                  // h1(kt) ready (staged P4(kt-1))
    BARRIER();
    __builtin_amdgcn_s_setprio(1);
#pragma unroll
    for (int mo = 0; mo < 4; ++mo)
#pragma unroll
      for (int no = 0; no < 2; ++no)
#pragma unroll
        for (int ks = 0; ks < 2; ++ks)
          acc[mo * 2][no * 2] = __builtin_amdgcn_mfma_f32_16x16x32_bf16(
              afr[mo][ks], bfr0[no][ks], acc[mo * 2][no * 2], 0, 0, 0);
    __builtin_amdgcn_s_setprio(0);
    BARRIER();

    // ===== P2: (mp0, np1) — reads Bh1(kt); stage h0(kt+1) into freed slots
#pragma unroll
    for (int no = 0; no < 2; ++no)
#pragma unroll
      for (int ks = 0; ks < 2; ++ks)
        bfr1[no][ks] = lds_frag(bB, wc4 + no * 2 + 1, 1, ks, l15, kg, l7);
    if (st) {
      stage_half(gA, kt + 1, 0, bA, wave, lane);
      stage_half(gB, kt + 1, 0, bB, wave, lane);
    }
    BARRIER();
    __builtin_amdgcn_s_setprio(1);
#pragma unroll
    for (int mo = 0; mo < 4; ++mo)
#pragma unroll
      for (int no = 0; no < 2; ++no)
#pragma unroll
        for (int ks = 0; ks < 2; ++ks)
          acc[mo * 2][no * 2 + 1] = __builtin_amdgcn_mfma_f32_16x16x32_bf16(
              afr[mo][ks], bfr1[no][ks], acc[mo * 2][no * 2 + 1], 0, 0, 0);
    __builtin_amdgcn_s_setprio(0);
    BARRIER();

    // ===== P3: (mp1, np0) — reads Ah1(kt); bfr0 kept live from P1
#pragma unroll
    for (int mo = 0; mo < 4; ++mo)
#pragma unroll
      for (int ks = 0; ks < 2; ++ks)
        afr[mo][ks] = lds_frag(bA, wr8 + mo * 2 + 1, 1, ks, l15, kg, l7);
    BARRIER();
    __builtin_amdgcn_s_setprio(1);
#pragma unroll
    for (int mo = 0; mo < 4; ++mo)
#pragma unroll
      for (int no = 0; no < 2; ++no)
#pragma unroll
        for (int ks = 0; ks < 2; ++ks)
          acc[mo * 2 + 1][no * 2] = __builtin_amdgcn_mfma_f32_16x16x32_bf16(
              afr[mo][ks], bfr0[no][ks], acc[mo * 2 + 1][no * 2], 0, 0, 0);
    __builtin_amdgcn_s_setprio(0);
    BARRIER();

    // ===== P4: (mp1, np1) — stage h1(kt+1) into freed slots
    if (st) {
      stage_half(gA, kt + 1, 1, bA, wave, lane);
      stage_half(gB, kt + 1, 1, bB, wave, lane);
      VMCNT(4);                // h0(kt+1) ready (staged P2, 2-phase cover);
                               // h1(kt+1) stays in flight
    }
    BARRIER();
    __builtin_amdgcn_s_setprio(1);
#pragma unroll
    for (int mo = 0; mo < 4; ++mo)
#pragma unroll
      for (int no = 0; no < 2; ++no)
#pragma unroll
        for (int ks = 0; ks < 2; ++ks)
          acc[mo * 2 + 1][no * 2 + 1] = __builtin_amdgcn_mfma_f32_16x16x32_bf16(
              afr[mo][ks], bfr1[no][ks], acc[mo * 2 + 1][no * 2 + 1], 0, 0, 0);
    __builtin_amdgcn_s_setprio(0);
    BARRIER();
  }

  // ---- epilogue: C/D layout col=lane&15, row=(lane>>4)*4+j (m89-verified)
  const int crow0 = mt * BM + wr * 128 + (lane >> 4) * 4;
  const int ccol0 = nt * BN + wc * 64 + (lane & 15);
#pragma unroll
  for (int m = 0; m < 8; ++m) {
#pragma unroll
    for (int j = 0; j < 4; ++j) {
      size_t rowoff =
          ((size_t)(crow0 + m * 16 + j) * T_DIM + t) * OUT_DIM + ccol0;
#pragma unroll
      for (int n = 0; n < 4; ++n)
        O[rowoff + n * 16] = acc[m][n][j];
    }
  }
}

// ---- host ------------------------------------------------------------------
extern "C" void kernel_launch(void* const* d_in, const int* in_sizes, int n_in,
                              void* d_out, int out_size, void* d_ws, size_t ws_size,
                              hipStream_t stream) {
  const float* x      = (const float*)d_in[0];
  const float* first  = (const float*)d_in[1];
  const float* middle = (const float*)d_in[2];
  const float* task   = (const float*)d_in[3];
  float* out = (float*)d_out;

  // ws: a1 fp32 1MB @0; wT bf16 16MB @1MB; xb bf16 64MB @17MB
  float* a1 = (float*)d_ws;
  __hip_bfloat16* wT = (__hip_bfloat16*)((uint8_t*)d_ws + (1u << 20));
  uint16_t* xb = (uint16_t*)((uint8_t*)d_ws + (17u << 20));

  hipFuncSetAttribute((const void*)tt_gemm,
                      hipFuncAttributeMaxDynamicSharedMemorySize, 65536);

  // L1: stage1 + cvt(t0-3)   (3072 blocks)
  pre1<<<3072, 256, 0, stream>>>(first, middle, a1, x, xb);
  // L2: stage2 + cvt(t4-7)   (4096 blocks)
  pre2<<<4096, 256, 0, stream>>>(a1, task, wT, x, xb);
  // L3: single 512-block GEMM, 64KB LDS + 128 VGPR -> 2 blocks/CU
  tt_gemm<<<T_DIM * (B_DIM / BM) * (OUT_DIM / BN), 512, 65536, stream>>>(
      xb, (const uint16_t*)wT, out);
}

// Round 11
// 136.284 us; speedup vs baseline: 4.3064x; 1.1183x over previous
//
#include <hip/hip_runtime.h>
#include <hip/hip_bf16.h>
#include <stdint.h>

#define B_DIM 4096
#define T_DIM 8
#define IN_DIM 1024
#define OUT_DIM 1024
#define R_DIM 32

#define BM 256
#define BN 256
#define BK 64
#define NKT (IN_DIM / BK)   // 16

typedef __bf16 bf16x8 __attribute__((ext_vector_type(8)));
typedef float  f32x4  __attribute__((ext_vector_type(4)));

#define VMCNT(n) asm volatile("s_waitcnt vmcnt(" #n ")" ::: "memory")
#define CFENCE() asm volatile("" ::: "memory")
#define BARRIER() do { CFENCE(); __builtin_amdgcn_s_barrier(); CFENCE(); } while (0)

// ---- helpers --------------------------------------------------------------

// async global->LDS, 16B per lane; LDS dest is wave-uniform base + lane*16
__device__ __forceinline__ void gload_lds16(const void* g, void* l) {
  __builtin_amdgcn_global_load_lds(
      (const __attribute__((address_space(1))) void*)(uintptr_t)g,
      (__attribute__((address_space(3))) void*)(uint32_t)(uintptr_t)l,
      16, 0, 0);
}

// ---- B staging: 16KB bf16 half-tile (128 rows, 16-row interleave) ---------
// LDS dest linear; source chunk pre-swizzled (chunk ^= slot&7).  [R10-proven]
__device__ __forceinline__ void stage_half_b(const uint16_t* gtile, int ktn,
                                             int half, uint8_t* ldsop,
                                             int wave, int lane) {
#pragma unroll
  for (int j = 0; j < 2; ++j) {
    int s = j * 64 + wave * 8 + (lane >> 3);      // slot 0..127 within half
    int c = lane & 7;                             // 16B chunk (row = 128B)
    int row = (s >> 4) * 32 + half * 16 + (s & 15);
    gload_lds16((const uint8_t*)(gtile + (size_t)row * IN_DIM + ktn * BK) +
                    ((c ^ (s & 7)) << 4),
                ldsop + half * 16384 + j * 8192 + wave * 1024);
  }
}

// ---- A staging: 32KB fp32 half-tile (128 rows x 64k x 4B; 256B rows) ------
// rows 16-row interleaved (half=(row>>4)&1); 16 chunks/row, chunk ^= slot&7.
// xpanel = &X[((mt*BM)*T_DIM + t)*IN_DIM] (row stride T_DIM*IN_DIM floats).
__device__ __forceinline__ void stage_half_a(const float* xpanel, int ktn,
                                             int half, uint8_t* ldsA,
                                             int wave, int lane) {
#pragma unroll
  for (int j = 0; j < 4; ++j) {
    int s = j * 32 + wave * 4 + (lane >> 4);      // slot 0..127 within half
    int c = lane & 15;                            // 16B chunk (row = 256B)
    int row = (s >> 4) * 32 + half * 16 + (s & 15);
    gload_lds16(xpanel + (size_t)row * (T_DIM * IN_DIM) + ktn * BK +
                    ((c ^ (s & 7)) << 2),
                ldsA + half * 32768 + j * 8192 + wave * 1024);
  }
}

// B fragment read: grp = wc4 + no*2 (+par); addr proven in R10.
__device__ __forceinline__ bf16x8 b_frag(const uint8_t* opB, int grp, int par,
                                         int ks, int l15, int kg, int l7) {
  return *(const bf16x8*)(opB + par * 16384 + (grp >> 1) * 2048 + l15 * 128 +
                          ((((ks << 2) + kg) ^ l7) << 4));
}

// A fragment read + fp32->bf16 truncation via v_perm (R3-verified numerics).
// row = wr*128 + mo*32 + half*16 + l15 -> slot byte = (wr*4+mo)*4096+l15*256.
// floats k = ks*32+kg*8 .. +7 -> chunks c0=ks*8+kg*2 and c0+1 (pre-XOR l7).
__device__ __forceinline__ bf16x8 a_frag(const uint8_t* opA, int grp2, int half,
                                         int ks, int l15, int kg, int l7) {
  const uint8_t* base = opA + half * 32768 + grp2 * 4096 + l15 * 256;
  const int c0 = ks * 8 + kg * 2;
  f32x4 lo = *(const f32x4*)(base + (((c0    ) ^ l7) << 4));
  f32x4 hi = *(const f32x4*)(base + (((c0 + 1) ^ l7) << 4));
  union { uint32_t u[4]; bf16x8 v; } cv;
  cv.u[0] = __builtin_amdgcn_perm(__float_as_uint(lo.y), __float_as_uint(lo.x), 0x07060302u);
  cv.u[1] = __builtin_amdgcn_perm(__float_as_uint(lo.w), __float_as_uint(lo.z), 0x07060302u);
  cv.u[2] = __builtin_amdgcn_perm(__float_as_uint(hi.y), __float_as_uint(hi.x), 0x07060302u);
  cv.u[3] = __builtin_amdgcn_perm(__float_as_uint(hi.w), __float_as_uint(hi.z), 0x07060302u);
  return cv.v;
}

// ---- kernel 1: A1[t][i][k] = sum_j first[t][j] * middle[j][i][k] ----------
__global__ void tt_stage1(const float* __restrict__ first,
                          const float* __restrict__ middle,
                          float* __restrict__ a1) {
  int idx = blockIdx.x * 256 + threadIdx.x;     // t*32768 + i*32 + k
  int t  = idx >> 15;
  int ik = idx & 32767;
  float acc = 0.f;
#pragma unroll
  for (int j = 0; j < R_DIM; ++j)
    acc = fmaf(first[t * R_DIM + j], middle[j * (IN_DIM * R_DIM) + ik], acc);
  a1[idx] = acc;
}

// ---- kernel 2: w_T[t][o][i] = sum_k A1[t][i][k]*task[k][o], bf16 ----------
__global__ __launch_bounds__(256) void tt_stage2(const float* __restrict__ a1,
                                                 const float* __restrict__ task,
                                                 __hip_bfloat16* __restrict__ wT) {
  int bid = blockIdx.x;
  int t  = bid >> 8;
  int ob = (bid >> 4) & 15;
  int ib = bid & 15;
  __shared__ float A1s[64][33];
  __shared__ float Ts[32][64];
  int tid = threadIdx.x;
#pragma unroll
  for (int r = 0; r < 8; ++r) {
    int idx2 = tid + 256 * r;              // 64x32 A1 tile
    int il = idx2 >> 5, k = idx2 & 31;
    A1s[il][k] = a1[t * (IN_DIM * R_DIM) + (ib * 64 + il) * R_DIM + k];
  }
#pragma unroll
  for (int r = 0; r < 8; ++r) {
    int idx2 = tid + 256 * r;              // 32x64 task tile
    int k = idx2 >> 6, ol = idx2 & 63;
    Ts[k][ol] = task[k * OUT_DIM + ob * 64 + ol];
  }
  __syncthreads();
  int il = tid & 63;
  int og = tid >> 6;                        // 0..3
  float acc[16];
#pragma unroll
  for (int r = 0; r < 16; ++r) acc[r] = 0.f;
#pragma unroll
  for (int k = 0; k < 32; ++k) {
    float a = A1s[il][k];
#pragma unroll
    for (int r = 0; r < 16; ++r)
      acc[r] = fmaf(a, Ts[k][og * 16 + r], acc[r]);
  }
#pragma unroll
  for (int r = 0; r < 16; ++r) {
    size_t o = (size_t)ob * 64 + og * 16 + r;
    wT[((size_t)t * OUT_DIM + o) * IN_DIM + ib * 64 + il] = __float2bfloat16(acc[r]);
  }
}

// ---- kernel 3: fused GEMM, A = raw fp32 x via gload_lds, cvt at frag-read -
// 256x256xBK64, 8-phase half-ping-pong (R10 schedule, 96KB LDS, 1 blk/CU):
//   LDS: A fp32 h0 @0 (32K), h1 @32K; B bf16 h0 @64K (16K), h1 @80K.
//   h0(kt) last read P1 -> stage h0(kt+1) in P2 (Ah0 4 + Bh0 2 gloads);
//   h1(kt) last read P2/P3 -> stage h1(kt+1) in P4 (Ah1 4 + Bh1 2).
//   Waits: P4-end VMCNT(6) (h0(kt+1) ready, h1 flying); P1-end VMCNT(0).
// No xb pass: saves 192MB cvt traffic + one launch; A fetch 2x (fp32) but
// nt-fastest + t==XCD keeps panels L2-shared. cvt = 4 v_perm/frag (trunc).
__global__ __launch_bounds__(512, 2) void tt_gemm(const float* __restrict__ X,
                                                  const uint16_t* __restrict__ WT,
                                                  float* __restrict__ O) {
  extern __shared__ uint8_t sm[];
  int bid = blockIdx.x;
  const int t  = bid & 7;                 // task == XCD (round-robin dispatch)
  const int l  = bid >> 3;                // 0..63 within task
  const int mt = l >> 2;                  // 0..15
  const int nt = l & 3;                   // n-fastest: x panel L2-shared

  const int tid  = threadIdx.x;
  const int lane = tid & 63;
  const int wave = tid >> 6;              // 0..7
  const int wr = wave >> 2, wc = wave & 3;
  const int wc4 = wc * 4;
  const int l15 = lane & 15, l7 = lane & 7, kg = lane >> 4;

  const float* xpanel = X + ((size_t)(mt * BM) * T_DIM + t) * IN_DIM;
  const uint16_t* gB = WT + ((size_t)t * OUT_DIM + nt * BN) * IN_DIM;

  uint8_t* bA = sm;            // fp32 A: h0 @0, h1 @32768
  uint8_t* bB = sm + 65536;    // bf16 B: h0 @0, h1 @16384

  f32x4 acc[8][4] = {};
  bf16x8 afr[4][2], bfr0[2][2], bfr1[2][2];

  // ---- prologue: K-tile 0, both halves; drain h0 (h1 drains at P1-end)
  stage_half_a(xpanel, 0, 0, bA, wave, lane);
  stage_half_b(gB, 0, 0, bB, wave, lane);
  stage_half_a(xpanel, 0, 1, bA, wave, lane);
  stage_half_b(gB, 0, 1, bB, wave, lane);
  VMCNT(6);                    // h0(0) ready; h1(0) still flying
  BARRIER();

  for (int kt = 0; kt < NKT; ++kt) {
    const bool st = (kt + 1) < NKT;

    // ===== P1: (mp0, np0) — reads h0(kt); h0 free after this phase
#pragma unroll
    for (int mo = 0; mo < 4; ++mo)
#pragma unroll
      for (int ks = 0; ks < 2; ++ks)
        afr[mo][ks] = a_frag(bA, wr * 4 + mo, 0, ks, l15, kg, l7);
#pragma unroll
    for (int no = 0; no < 2; ++no)
#pragma unroll
      for (int ks = 0; ks < 2; ++ks)
        bfr0[no][ks] = b_frag(bB, wc4 + no * 2, 0, ks, l15, kg, l7);
    VMCNT(0);                  // h1(kt) ready (staged P4(kt-1))
    BARRIER();
    __builtin_amdgcn_s_setprio(1);
#pragma unroll
    for (int mo = 0; mo < 4; ++mo)
#pragma unroll
      for (int no = 0; no < 2; ++no)
#pragma unroll
        for (int ks = 0; ks < 2; ++ks)
          acc[mo * 2][no * 2] = __builtin_amdgcn_mfma_f32_16x16x32_bf16(
              afr[mo][ks], bfr0[no][ks], acc[mo * 2][no * 2], 0, 0, 0);
    __builtin_amdgcn_s_setprio(0);
    BARRIER();

    // ===== P2: (mp0, np1) — reads Bh1(kt); stage h0(kt+1) into freed slots
#pragma unroll
    for (int no = 0; no < 2; ++no)
#pragma unroll
      for (int ks = 0; ks < 2; ++ks)
        bfr1[no][ks] = b_frag(bB, wc4 + no * 2 + 1, 1, ks, l15, kg, l7);
    if (st) {
      stage_half_a(xpanel, kt + 1, 0, bA, wave, lane);
      stage_half_b(gB, kt + 1, 0, bB, wave, lane);
    }
    BARRIER();
    __builtin_amdgcn_s_setprio(1);
#pragma unroll
    for (int mo = 0; mo < 4; ++mo)
#pragma unroll
      for (int no = 0; no < 2; ++no)
#pragma unroll
        for (int ks = 0; ks < 2; ++ks)
          acc[mo * 2][no * 2 + 1] = __builtin_amdgcn_mfma_f32_16x16x32_bf16(
              afr[mo][ks], bfr1[no][ks], acc[mo * 2][no * 2 + 1], 0, 0, 0);
    __builtin_amdgcn_s_setprio(0);
    BARRIER();

    // ===== P3: (mp1, np0) — reads Ah1(kt); bfr0 kept live from P1
#pragma unroll
    for (int mo = 0; mo < 4; ++mo)
#pragma unroll
      for (int ks = 0; ks < 2; ++ks)
        afr[mo][ks] = a_frag(bA, wr * 4 + mo, 1, ks, l15, kg, l7);
    BARRIER();
    __builtin_amdgcn_s_setprio(1);
#pragma unroll
    for (int mo = 0; mo < 4; ++mo)
#pragma unroll
      for (int no = 0; no < 2; ++no)
#pragma unroll
        for (int ks = 0; ks < 2; ++ks)
          acc[mo * 2 + 1][no * 2] = __builtin_amdgcn_mfma_f32_16x16x32_bf16(
              afr[mo][ks], bfr0[no][ks], acc[mo * 2 + 1][no * 2], 0, 0, 0);
    __builtin_amdgcn_s_setprio(0);
    BARRIER();

    // ===== P4: (mp1, np1) — stage h1(kt+1) into freed slots
    if (st) {
      stage_half_a(xpanel, kt + 1, 1, bA, wave, lane);
      stage_half_b(gB, kt + 1, 1, bB, wave, lane);
    }
    VMCNT(6);                  // h0(kt+1) ready (staged P2, 2-phase cover);
                               // h1(kt+1) stays in flight
    BARRIER();
    __builtin_amdgcn_s_setprio(1);
#pragma unroll
    for (int mo = 0; mo < 4; ++mo)
#pragma unroll
      for (int no = 0; no < 2; ++no)
#pragma unroll
        for (int ks = 0; ks < 2; ++ks)
          acc[mo * 2 + 1][no * 2 + 1] = __builtin_amdgcn_mfma_f32_16x16x32_bf16(
              afr[mo][ks], bfr1[no][ks], acc[mo * 2 + 1][no * 2 + 1], 0, 0, 0);
    __builtin_amdgcn_s_setprio(0);
    BARRIER();
  }

  // ---- epilogue: C/D layout col=lane&15, row=(lane>>4)*4+j (m89-verified)
  const int crow0 = mt * BM + wr * 128 + (lane >> 4) * 4;
  const int ccol0 = nt * BN + wc * 64 + (lane & 15);
#pragma unroll
  for (int m = 0; m < 8; ++m) {
#pragma unroll
    for (int j = 0; j < 4; ++j) {
      size_t rowoff =
          ((size_t)(crow0 + m * 16 + j) * T_DIM + t) * OUT_DIM + ccol0;
#pragma unroll
      for (int n = 0; n < 4; ++n)
        O[rowoff + n * 16] = acc[m][n][j];
    }
  }
}

// ---- host ------------------------------------------------------------------
extern "C" void kernel_launch(void* const* d_in, const int* in_sizes, int n_in,
                              void* d_out, int out_size, void* d_ws, size_t ws_size,
                              hipStream_t stream) {
  const float* x      = (const float*)d_in[0];
  const float* first  = (const float*)d_in[1];
  const float* middle = (const float*)d_in[2];
  const float* task   = (const float*)d_in[3];
  float* out = (float*)d_out;

  // ws: a1 fp32 1MB @0; wT bf16 16MB @1MB   (no xb anymore)
  float* a1 = (float*)d_ws;
  __hip_bfloat16* wT = (__hip_bfloat16*)((uint8_t*)d_ws + (1u << 20));

  hipFuncSetAttribute((const void*)tt_gemm,
                      hipFuncAttributeMaxDynamicSharedMemorySize, 98304);

  tt_stage1<<<(T_DIM * IN_DIM * R_DIM) / 256, 256, 0, stream>>>(first, middle, a1);
  tt_stage2<<<T_DIM * 16 * 16, 256, 0, stream>>>(a1, task, wT);
  tt_gemm<<<T_DIM * (B_DIM / BM) * (OUT_DIM / BN), 512, 98304, stream>>>(
      x, (const uint16_t*)wT, out);
}